// Round 12
// baseline (80.985 us; speedup 1.0000x reference)
//
#include <hip/hip_runtime.h>
#include <hip/hip_bf16.h>

#define N_TOTAL 4096
#define C_DIM 256
#define K_NEG 128
#define HW 1024
#define TEMP_INV (1.0f / 0.07f)

typedef _Float16 h8 __attribute__((ext_vector_type(8)));
typedef _Float16 h2 __attribute__((ext_vector_type(2)));

// ---------------------------------------------------------------------------
// Kernel 1: normalize + transpose, single pass (r9 version, proven).
// q rows carry 1/T; k rows plain normalized f16.
// ---------------------------------------------------------------------------
__global__ __launch_bounds__(256) void norm_tr_kernel(
    const float* __restrict__ fq, const float* __restrict__ fk,
    _Float16* __restrict__ qh, _Float16* __restrict__ kh) {
  const int bid = blockIdx.x;
  const int tensor = bid >> 8;         // 0=q, 1=k
  const int chunk = bid & 255;         // 16-row chunk
  const int n0 = chunk * 16;
  const int b = n0 / HW, s0 = n0 % HW;
  const float* base = (tensor ? fk : fq) + (size_t)b * C_DIM * HW + s0;
  _Float16* out = tensor ? kh : qh;
  const float scale_extra = tensor ? 1.0f : TEMP_INV;

  const int t = threadIdx.x;
  __shared__ float tile[16][C_DIM + 1];
  __shared__ float red[16][17];
  __shared__ float sinv[16];

  {
    const float* src = base + (size_t)t * HW;
#pragma unroll
    for (int p = 0; p < 4; ++p) {
      const float4 v = *(const float4*)(src + p * 4);
      tile[p * 4 + 0][t] = v.x;
      tile[p * 4 + 1][t] = v.y;
      tile[p * 4 + 2][t] = v.z;
      tile[p * 4 + 3][t] = v.w;
    }
  }
  __syncthreads();

  {
    const int s = t & 15, cg = t >> 4;
    float acc = 0.f;
#pragma unroll
    for (int i = 0; i < 16; ++i) {
      float v = tile[s][cg * 16 + i];
      acc = fmaf(v, v, acc);
    }
    red[s][cg] = acc;
  }
  __syncthreads();
  if (t < 16) {
    float tot = 0.f;
#pragma unroll
    for (int g = 0; g < 16; ++g) tot += red[t][g];
    sinv[t] = scale_extra / fmaxf(sqrtf(tot), 1e-12f);  // eps = 1e-12
  }
  __syncthreads();

  {
    const int s = t & 15, c16 = t >> 4;
    const float inv = sinv[s];
    h8 o0, o1;
#pragma unroll
    for (int j = 0; j < 8; ++j) o0[j] = (_Float16)(tile[s][c16 * 16 + j] * inv);
#pragma unroll
    for (int j = 0; j < 8; ++j)
      o1[j] = (_Float16)(tile[s][c16 * 16 + 8 + j] * inv);
    h8* dst = (h8*)(out + (size_t)(n0 + s) * C_DIM + c16 * 16);
    dst[0] = o0;
    dst[1] = o1;
  }
}

// ---------------------------------------------------------------------------
// Kernel 2: per-WAVE InfoNCE, fully resident grid, no LDS, no barriers.
// 512 blocks x 8 waves; wave = one row. 8-lane unit handles 16 negatives
// sequentially with an ONLINE logsumexp (running m,s registers; no logit
// array, no wave-0 tail). Cross-unit merge via 3 shfl_xor steps.
// r11 evidence: gather is neither bytes- nor request-bound; the fixed cost
// was per-block serialization -- this removes block lifecycle entirely.
// ---------------------------------------------------------------------------
__global__ __launch_bounds__(512, 4) void nce_kernel(
    const _Float16* __restrict__ qh, const _Float16* __restrict__ kh,
    const int* __restrict__ neg, float* __restrict__ loss_buf) {
  const int tid = threadIdx.x;
  const int w = tid >> 6, lane = tid & 63;
  const int sub = lane & 7;            // lane within 8-lane unit
  const int unit = lane >> 3;          // 0..7
  const int n = blockIdx.x * 8 + w;

  union H { h8 v; h2 p[4]; };

  // q row (1/T folded): lane sub owns chunks {sub, 8+sub, 16+sub, 24+sub}
  const h8* qrow = (const h8*)(qh + (size_t)n * C_DIM);
  h8 qv[4];
#pragma unroll
  for (int i = 0; i < 4; ++i) qv[i] = qrow[i * 8 + sub];
  // positive k row (same chunks; all units broadcast-read the same addrs)
  const h8* kpr = (const h8*)(kh + (size_t)n * C_DIM);
  h8 kp[4];
#pragma unroll
  for (int i = 0; i < 4; ++i) kp[i] = kpr[i * 8 + sub];

  const int* nrow = neg + (size_t)n * K_NEG + unit * 16;

  float m = -1e30f, s = 0.f;
#pragma unroll 2
  for (int j = 0; j < 16; ++j) {
    const int x = nrow[j];               // broadcast within unit
    const int r = x + (x >= n ? 1 : 0);  // self-exclusion shift
    const h8* kr = (const h8*)(kh + (size_t)r * C_DIM);
    float a0 = 0.f, a1 = 0.f;
#pragma unroll
    for (int i = 0; i < 4; ++i) {
      H a; a.v = qv[i];
      H b; b.v = kr[i * 8 + sub];        // 128B contiguous per unit
      a0 = __builtin_amdgcn_fdot2(b.p[0], a.p[0], a0, false);
      a1 = __builtin_amdgcn_fdot2(b.p[1], a.p[1], a1, false);
      a0 = __builtin_amdgcn_fdot2(b.p[2], a.p[2], a0, false);
      a1 = __builtin_amdgcn_fdot2(b.p[3], a.p[3], a1, false);
    }
    float acc = a0 + a1;
    acc += __shfl_xor(acc, 1);
    acc += __shfl_xor(acc, 2);
    acc += __shfl_xor(acc, 4);
    // online LSE update (uniform across the unit's 8 lanes)
    const float mn = fmaxf(m, acc);
    s = s * __expf(m - mn) + __expf(acc - mn);
    m = mn;
  }

  // positive logit (every unit computes it redundantly; broadcast loads)
  float lp;
  {
    float a0 = 0.f, a1 = 0.f;
#pragma unroll
    for (int i = 0; i < 4; ++i) {
      H a; a.v = qv[i];
      H b; b.v = kp[i];
      a0 = __builtin_amdgcn_fdot2(b.p[0], a.p[0], a0, false);
      a1 = __builtin_amdgcn_fdot2(b.p[1], a.p[1], a1, false);
      a0 = __builtin_amdgcn_fdot2(b.p[2], a.p[2], a0, false);
      a1 = __builtin_amdgcn_fdot2(b.p[3], a.p[3], a1, false);
    }
    float acc = a0 + a1;
    acc += __shfl_xor(acc, 1);
    acc += __shfl_xor(acc, 2);
    acc += __shfl_xor(acc, 4);
    lp = acc;
  }

  // merge the 8 units' (m,s) pairs across the wave
#pragma unroll
  for (int off = 8; off <= 32; off <<= 1) {
    const float mo = __shfl_xor(m, off);
    const float so = __shfl_xor(s, off);
    const float mn = fmaxf(m, mo);
    s = s * __expf(m - mn) + so * __expf(mo - mn);
    m = mn;
  }
  const float M = fmaxf(m, lp);
  const float stot = s * __expf(m - M) + __expf(lp - M);
  if (lane == 0) loss_buf[n] = M + __logf(stot) - lp;
}

// ---------------------------------------------------------------------------
// Kernel 3: mean over 4096 per-row losses. One block, 1024 threads.
// ---------------------------------------------------------------------------
__global__ __launch_bounds__(1024) void reduce_kernel(
    const float* __restrict__ loss_buf, float* __restrict__ out) {
  const int t = threadIdx.x;
  const float4 v = ((const float4*)loss_buf)[t];
  float s = (v.x + v.y) + (v.z + v.w);
#pragma unroll
  for (int off = 32; off; off >>= 1) s += __shfl_xor(s, off);
  __shared__ float red[16];
  if ((t & 63) == 0) red[t >> 6] = s;
  __syncthreads();
  if (t < 16) {
    float x = red[t];
#pragma unroll
    for (int off = 8; off; off >>= 1) x += __shfl_xor(x, off);
    if (t == 0) out[0] = x * (1.0f / N_TOTAL);
  }
}

extern "C" void kernel_launch(void* const* d_in, const int* in_sizes, int n_in,
                              void* d_out, int out_size, void* d_ws,
                              size_t ws_size, hipStream_t stream) {
  const float* fq = (const float*)d_in[0];
  const float* fk = (const float*)d_in[1];
  const int* neg = (const int*)d_in[2];
  float* out = (float*)d_out;

  _Float16* qh = (_Float16*)d_ws;                            // 2 MiB
  _Float16* kh = qh + (size_t)N_TOTAL * C_DIM;               // 2 MiB
  float* loss_buf = (float*)(kh + (size_t)N_TOTAL * C_DIM);  // 16 KiB

  hipLaunchKernelGGL(norm_tr_kernel, dim3(512), dim3(256), 0, stream,
                     fq, fk, qh, kh);
  hipLaunchKernelGGL(nce_kernel, dim3(N_TOTAL / 8), dim3(512), 0, stream,
                     qh, kh, neg, loss_buf);
  hipLaunchKernelGGL(reduce_kernel, dim3(1), dim3(1024), 0, stream,
                     loss_buf, out);
}